// Round 15
// baseline (123.226 us; speedup 1.0000x reference)
//
#include <hip/hip_runtime.h>
#include <hip/hip_bf16.h>

#define S_LEN 2048
#define DM    512
#define NH    8
#define DH    64

typedef float  f4   __attribute__((ext_vector_type(4)));
typedef float  f16v __attribute__((ext_vector_type(16)));
typedef short  s8v  __attribute__((ext_vector_type(8)));
typedef __bf16 b8v  __attribute__((ext_vector_type(8)));
union F8 { s8v s; b8v b; };
union U4 { unsigned u[4]; s8v s; b8v b; };

typedef __attribute__((address_space(1))) const void gas_t;
typedef __attribute__((address_space(3))) void       las_t;

__device__ __forceinline__ void gl16(const void* g, void* l) {
  __builtin_amdgcn_global_load_lds((gas_t*)g, (las_t*)l, 16, 0, 0);
}

__device__ __forceinline__ ushort f2bf(float x) {
  unsigned u = __float_as_uint(x);
  u += 0x7FFFu + ((u >> 16) & 1u);   // round-to-nearest-even
  return (ushort)(u >> 16);
}
// packed f32x2 -> bf16x2, RNE (compiler path per m240)
__device__ __forceinline__ unsigned pk2(float a, float b) {
  union { __hip_bfloat162 h; unsigned u; } cv;
  cv.h = __float22bfloat162_rn(make_float2(a, b));
  return cv.u;
}
// packed f32x2 -> bf16x2 by TRUNCATION: single v_perm_b32.
// (round-bias is pre-compensated in the exp2 constant C2')
__device__ __forceinline__ unsigned pkt(float a, float b) {
  return __builtin_amdgcn_perm(__float_as_uint(b), __float_as_uint(a),
                               0x07060302u);
}
// 1-instr exp2
__device__ __forceinline__ float ex2(float x) {
#if __has_builtin(__builtin_amdgcn_exp2f)
  return __builtin_amdgcn_exp2f(x);
#else
  return exp2f(x);
#endif
}

// (r_lo, r_hi) = permlane32_swap(a, b)
__device__ __forceinline__ void plswap(unsigned a, unsigned b,
                                       unsigned& lo, unsigned& hi2) {
#if __has_builtin(__builtin_amdgcn_permlane32_swap)
  auto r = __builtin_amdgcn_permlane32_swap((int)a, (int)b, false, false);
  lo  = (unsigned)r[0];
  hi2 = (unsigned)r[1];
#else
  const bool ish = (threadIdx.x & 32) != 0;
  const unsigned sa = (unsigned)__shfl_xor((int)a, 32);
  const unsigned sb = (unsigned)__shfl_xor((int)b, 32);
  lo  = ish ? sb : a;
  hi2 = ish ? b  : sa;
#endif
}

// --- slim prep: mask nonzero scan + weight transpose ---
__global__ void prep(const float* __restrict__ mask,
                     const float* __restrict__ w0, const float* __restrict__ w1,
                     const float* __restrict__ w2, const float* __restrict__ w3,
                     ushort* __restrict__ o0, ushort* __restrict__ o1,
                     ushort* __restrict__ o2, ushort* __restrict__ o3,
                     int* __restrict__ flag) {
  const int z = blockIdx.y;
  if (z == 2) {
    const int bx = blockIdx.x;
    if (bx >= 1024) return;
    const int w = bx >> 8;
    const float* src = (w == 0) ? w0 : (w == 1) ? w1 : (w == 2) ? w2 : w3;
    ushort* dst = (w == 0) ? o0 : (w == 1) ? o1 : (w == 2) ? o2 : o3;
    __shared__ float tile[32][33];
    const int tx = threadIdx.x & 31, ty = threadIdx.x >> 5;   // 32 x 8
    const int k0 = (bx & 15) * 32, n0 = ((bx >> 4) & 15) * 32;
#pragma unroll
    for (int i = 0; i < 4; ++i)
      tile[ty + i * 8][tx] = src[(size_t)(k0 + ty + i * 8) * DM + n0 + tx];
    __syncthreads();
#pragma unroll
    for (int i = 0; i < 4; ++i)
      dst[(size_t)(n0 + ty + i * 8) * DM + k0 + tx] = f2bf(tile[tx][ty + i * 8]);
    return;
  }
  const size_t i = (((size_t)z * 2048 + blockIdx.x) * 256 + threadIdx.x) * 4;
  const float4 m4 = *(const float4*)(mask + i);
  const bool nz = (m4.x != 0.f) | (m4.y != 0.f) | (m4.z != 0.f) | (m4.w != 0.f);
  if (nz) atomicOr(flag, 1);
}

// ------- QKV GEMM: fp32 A read + in-staging bf16 convert (reg-staged, T14),
// bf16 B via global_load_lds; 2-buf LDS; tn-siblings of a tm share an XCD -------
__global__ __launch_bounds__(256) void gemm_qkv(
    const float* __restrict__ Qf, const float* __restrict__ Kf,
    const float* __restrict__ Vf, const ushort* __restrict__ Wtq,
    const ushort* __restrict__ Wtk, const ushort* __restrict__ Wtv,
    const float* __restrict__ bq, const float* __restrict__ bk,
    const float* __restrict__ bv, ushort* __restrict__ Qh,
    ushort* __restrict__ Kh, ushort* __restrict__ Vt) {
  __shared__ ushort As[2 * 128 * 32], Bs[2 * 128 * 32];   // 2-buf, 32KB

  const int b = blockIdx.x;
  const int xcd = b & 7, i = b >> 3;               // i in [0,96)
  const int z = i >> 5, j = i & 31;
  const int tm = xcd * 8 + (j >> 2), tn = j & 3;
  const float* A = (z == 0) ? Qf : (z == 1) ? Kf : Vf;
  const ushort* Bt = (z == 0) ? Wtq : (z == 1) ? Wtk : Wtv;
  const float* bias = (z == 0) ? bq : (z == 1) ? bk : bv;
  ushort* out = (z == 0) ? Qh : (z == 1) ? Kh : Vt;
  const int mode = (z == 2) ? 1 : 0;

  const int tid  = threadIdx.x;
  const int lane = tid & 63, wave = tid >> 6;
  const int ql = lane & 15, lg = lane >> 4;
  const int wr = wave >> 1, wc = wave & 1;

  const int srow = wave * 32 + (lane >> 2);        // local staging row
  const float* gA0 = A + (size_t)(tm * 128 + srow) * 512 + (lane & 3) * 8;
  const float* gA1 = gA0 + 16 * 512;
  const char*  gB  = (const char*)(Bt + (size_t)(tn * 128 + srow) * 512) +
                     (lane & 3) * 16;

  float4 ar[4];
  auto loadA = [&](int kt) {                       // issue early: hides HBM lat
    const float* p0 = gA0 + kt * 32;
    const float* p1 = gA1 + kt * 32;
    ar[0] = *(const float4*)p0; ar[1] = *(const float4*)(p0 + 4);
    ar[2] = *(const float4*)p1; ar[3] = *(const float4*)(p1 + 4);
  };
  auto writeA = [&](int buf) {                     // cvt + ds_write (late)
    char* d = (char*)As + buf * 8192 + srow * 64 + (lane & 3) * 16;
    *(uint4*)d = make_uint4(pk2(ar[0].x, ar[0].y), pk2(ar[0].z, ar[0].w),
                            pk2(ar[1].x, ar[1].y), pk2(ar[1].z, ar[1].w));
    *(uint4*)(d + 16 * 64) =
        make_uint4(pk2(ar[2].x, ar[2].y), pk2(ar[2].z, ar[2].w),
                   pk2(ar[3].x, ar[3].y), pk2(ar[3].z, ar[3].w));
  };
  auto stageB = [&](int kt, int buf) {
    char* lB = (char*)Bs + buf * 8192 + wave * 2048;
    const size_t gofs = (size_t)kt * 64;
    gl16(gB + gofs, lB);
    gl16(gB + gofs + 16 * 512 * 2, lB + 1024);
  };

  f4 acc[4][4] = {};

  loadA(0);
  stageB(0, 0);
  writeA(0);
  __syncthreads();

  int cur = 0;
  for (int kt = 0; kt < 16; ++kt) {
    if (kt + 1 < 16) { loadA(kt + 1); stageB(kt + 1, cur ^ 1); }
    const ushort* Ab = As + cur * 4096;
    const ushort* Bb = Bs + cur * 4096;
    F8 af[4], bf[4];
#pragma unroll
    for (int ii = 0; ii < 4; ++ii) {
      af[ii].s = *(const s8v*)(Ab + (wr * 64 + ii * 16 + ql) * 32 + lg * 8);
      bf[ii].s = *(const s8v*)(Bb + (wc * 64 + ii * 16 + ql) * 32 + lg * 8);
    }
#pragma unroll
    for (int ii = 0; ii < 4; ++ii)
#pragma unroll
      for (int jj = 0; jj < 4; ++jj)
        acc[ii][jj] = __builtin_amdgcn_mfma_f32_16x16x32_bf16(
            af[ii].b, bf[jj].b, acc[ii][jj], 0, 0, 0);
    if (kt + 1 < 16) writeA(cur ^ 1);              // lands before next barrier
    __syncthreads();
    cur ^= 1;
  }

#pragma unroll
  for (int ii = 0; ii < 4; ++ii) {
#pragma unroll
    for (int jj = 0; jj < 4; ++jj) {
      const int n = tn * 128 + wc * 64 + jj * 16 + ql;
      const float bz = bias[n];
#pragma unroll
      for (int r = 0; r < 4; ++r) {
        const int m = tm * 128 + wr * 64 + ii * 16 + lg * 4 + r;
        const float val = acc[ii][jj][r] + bz;
        const int bb = m >> 11, s = m & 2047, h = n >> 6, d = n & 63;
        if (mode == 0)
          out[((size_t)(bb * NH + h) * S_LEN + s) * DH + d] = f2bf(val);
        else
          out[((size_t)(bb * NH + h) * DH + d) * S_LEN + s] = f2bf(val);
      }
    }
  }
}

// ------- output projection: 128x64 tiles, 2-phase staging -------
__global__ __launch_bounds__(256) void gemm_o2(
    const ushort* __restrict__ Obf, const ushort* __restrict__ Wto,
    const float* __restrict__ bo, float* __restrict__ out) {
  __shared__ ushort As[2 * 128 * 32];              // 2 x 8KB
  __shared__ ushort Bs[2 * 64 * 32];               // 2 x 4KB
  const int bidx = blockIdx.x;
  const int xcd = bidx & 7, ii = bidx >> 3;        // ii in [0,64)
  const int tm = xcd * 8 + (ii >> 3), tn = ii & 7;
  const int tid  = threadIdx.x;
  const int lane = tid & 63, wave = tid >> 6;
  const int ql = lane & 15, lg = lane >> 4;
  const int wr = wave >> 1, wc = wave & 1;

  const int rowA0 = tid >> 2,         offA0 = (tid & 3) * 16;
  const int rowA1 = (256 + tid) >> 2, offA1 = ((256 + tid) & 3) * 16;
  const int rowB  = tid >> 2,         offB  = (tid & 3) * 16;
  const char* gA0 = (const char*)(Obf + (size_t)(tm * 128 + rowA0) * 512) + offA0;
  const char* gA1 = (const char*)(Obf + (size_t)(tm * 128 + rowA1) * 512) + offA1;
  const char* gB  = (const char*)(Wto + (size_t)(tn * 64 + rowB) * 512) + offB;

  auto stage = [&](int kt, int buf) {
    const size_t gofs = (size_t)kt * 64;
    char* lA0 = (char*)As + buf * 8192 + wave * 1024;
    char* lA1 = (char*)As + buf * 8192 + 4096 + wave * 1024;
    char* lB  = (char*)Bs + buf * 4096 + wave * 1024;
    gl16(gA0 + gofs, lA0);
    gl16(gA1 + gofs, lA1);
    gl16(gB + gofs, lB);
  };

  f4 acc[4][2] = {};

  stage(0, 0);
  __syncthreads();

  int cur = 0;
  for (int kt = 0; kt < 16; ++kt) {
    if (kt + 1 < 16) stage(kt + 1, cur ^ 1);
    const ushort* Ab = As + cur * 4096;
    const ushort* Bb = Bs + cur * 2048;
    F8 af[4], bf[2];
#pragma unroll
    for (int i = 0; i < 4; ++i)
      af[i].s = *(const s8v*)(Ab + (wr * 64 + i * 16 + ql) * 32 + lg * 8);
#pragma unroll
    for (int j = 0; j < 2; ++j)
      bf[j].s = *(const s8v*)(Bb + (wc * 32 + j * 16 + ql) * 32 + lg * 8);
#pragma unroll
    for (int i = 0; i < 4; ++i)
#pragma unroll
      for (int j = 0; j < 2; ++j)
        acc[i][j] = __builtin_amdgcn_mfma_f32_16x16x32_bf16(af[i].b, bf[j].b,
                                                            acc[i][j], 0, 0, 0);
    __syncthreads();
    cur ^= 1;
  }

#pragma unroll
  for (int i = 0; i < 4; ++i)
#pragma unroll
    for (int j = 0; j < 2; ++j) {
      const int n = tn * 64 + wc * 32 + j * 16 + ql;
      const float bz = bo[n];
#pragma unroll
      for (int r = 0; r < 4; ++r) {
        const int m = tm * 128 + wr * 64 + i * 16 + lg * 4 + r;
        out[(size_t)m * DM + n] = acc[i][j][r] + bz;
      }
    }
}

// ------- flash attention: 2 q-streams/wave x kv-split halves -------
// grid = 512 (XCD-remapped, 32 bh * 16 qblocks of 128 q); 4 waves x 256thr.
// wave w: half=w>>1 (kv tiles half*16..+15), wq2=w&1 (q rows wq2*64..+63 as
// TWO 32-row streams). Each staged K/V tile is read by 2 waves (not 4) and
// each ds_read feeds 2 MFMAs -> LDS traffic halves, chain ILP doubles, while
// occupancy stays 2 blocks/CU (64KB LDS). Fixed-shift softmax => halves
// combine by pure addition via LDS overlay (exact).
__global__ __launch_bounds__(256, 2) void attn(
    const ushort* __restrict__ Qh, const ushort* __restrict__ Kh,
    const ushort* __restrict__ Vt, const float* __restrict__ mask,
    const int* __restrict__ flagp, ushort* __restrict__ Obf) {
  __shared__ char smem[65536];   // K[half][buf] 4x8KB | V[half][buf] 4x8KB

  const float K2 = 0.18033688011f;                 // 0.125 * log2(e)
  const float C2 = 17.3095245361f;                 // 12*log2(e) - log2(1+2^-9)

  const int bid = (blockIdx.x & 7) * 64 + (blockIdx.x >> 3);
  const int bh = bid >> 4, qb = bid & 15;
  const int tid = threadIdx.x, lane = tid & 63, w = tid >> 6;
  const int half = w >> 1, wq2 = w & 1;
  const int cl = lane & 31, hi = lane >> 5;
  const int qA = qb * 128 + wq2 * 64 + cl;         // stream A q row
  const int qB = qA + 32;                          // stream B q row
  const bool um = (*flagp) != 0;
  const char* KbC = (const char*)(Kh + (size_t)bh * S_LEN * DH);
  const char* VbC = (const char*)(Vt + (size_t)bh * DH * S_LEN);
  const unsigned swz = (unsigned)((cl & 7) << 4);

  char* kHalf = smem + half * 16384;               // 2 bufs of 8KB
  char* vHalf = smem + 32768 + half * 16384;

  // staging: tile = 512+512 16B-units; the 2 waves of a half stage it.
  // unit ui = c*128 + wq2*64 + lane; pre-swizzled global source offsets.
  int kofs[4], vofs[4];
#pragma unroll
  for (int c = 0; c < 4; ++c) {
    const int ui  = c * 128 + wq2 * 64 + lane;
    const int row = ui >> 3, u = ui & 7;
    const int xu  = u ^ (row & 7);
    kofs[c] = row * 128  + (xu << 4);              // K rows are 128B
    vofs[c] = row * 4096 + (xu << 4);              // V^T rows are S*2 = 4096B
  }

  // Q B-frags for both streams: lane holds Q[q][d = hi*8 + 16c .. +8]
  F8 qfA[4], qfB[4];
#pragma unroll
  for (int c = 0; c < 4; ++c) {
    qfA[c].s = *(const s8v*)(Qh + ((size_t)bh * S_LEN + qA) * DH + hi * 8 + 16 * c);
    qfB[c].s = *(const s8v*)(Qh + ((size_t)bh * S_LEN + qB) * DH + hi * 8 + 16 * c);
  }

  F8 ones;
#pragma unroll
  for (int i = 0; i < 8; ++i) ones.s[i] = (short)0x3F80;  // bf16 1.0

  f16v oA0 = {}, oA1 = {}, oB0 = {}, oB1 = {}, sA = {}, sB = {};

  auto stage = [&](int kt, int buf) {
    const char* kg = KbC + (size_t)kt * 8192;
    const char* vg = VbC + (size_t)kt * 128;
    char* kb = kHalf + buf * 8192 + wq2 * 1024;    // wave-uniform base
    char* vb = vHalf + buf * 8192 + wq2 * 1024;
#pragma unroll
    for (int c = 0; c < 4; ++c) {
      gl16(kg + kofs[c], kb + c * 2048);
      gl16(vg + vofs[c], vb + c * 2048);
    }
  };

  auto pack = [&](f16v& s0, f16v& s1, U4* pf) {
    unsigned P0[4][2], P1[4][2];
#pragma unroll
    for (int u = 0; u < 4; ++u)
#pragma unroll
      for (int e = 0; e < 2; ++e) {
        P0[u][e] = pkt(s0[4 * u + 2 * e], s0[4 * u + 2 * e + 1]);
        P1[u][e] = pkt(s1[4 * u + 2 * e], s1[4 * u + 2 * e + 1]);
      }
#pragma unroll
    for (int h2i = 0; h2i < 2; ++h2i)
#pragma unroll
      for (int e = 0; e < 2; ++e) {
        unsigned lo, h2;
        plswap(P0[2 * h2i][e], P0[2 * h2i + 1][e], lo, h2);
        pf[h2i].u[e] = lo; pf[h2i].u[2 + e] = h2;
        plswap(P1[2 * h2i][e], P1[2 * h2i + 1][e], lo, h2);
        pf[2 + h2i].u[e] = lo; pf[2 + h2i].u[2 + e] = h2;
      }
  };

  const int kt0 = half * 16;
  stage(kt0, 0);
  __syncthreads();

  int cur = 0;
  for (int t = 0; t < 16; ++t) {
    if (t + 1 < 16) stage(kt0 + t + 1, cur ^ 1);

    const char* KtB = kHalf + cur * 8192;
    const char* VtB = vHalf + cur * 8192;
    const int kv0 = (kt0 + t) * 64;

    // QK^T both streams: each ka read feeds 2 MFMAs
    const char* kr0 = KtB + (size_t)cl * 128;
    const char* kr1 = KtB + (size_t)(32 + cl) * 128;
    f16v sA0 = {}, sA1 = {}, sB0 = {}, sB1 = {};
    __builtin_amdgcn_s_setprio(1);
#pragma unroll
    for (int c = 0; c < 4; ++c) {
      const unsigned off = ((unsigned)(hi * 16 + 32 * c)) ^ swz;
      F8 ka0, ka1;
      ka0.s = *(const s8v*)(kr0 + off);
      ka1.s = *(const s8v*)(kr1 + off);
      sA0 = __builtin_amdgcn_mfma_f32_32x32x16_bf16(ka0.b, qfA[c].b, sA0, 0, 0, 0);
      sB0 = __builtin_amdgcn_mfma_f32_32x32x16_bf16(ka0.b, qfB[c].b, sB0, 0, 0, 0);
      sA1 = __builtin_amdgcn_mfma_f32_32x32x16_bf16(ka1.b, qfA[c].b, sA1, 0, 0, 0);
      sB1 = __builtin_amdgcn_mfma_f32_32x32x16_bf16(ka1.b, qfB[c].b, sB1, 0, 0, 0);
    }
    __builtin_amdgcn_s_setprio(0);

    if (um) {
#pragma unroll
      for (int r = 0; r < 16; ++r) {
        const int kvr = kv0 + (r & 3) + 8 * (r >> 2) + 4 * hi;
        sA0[r] += mask[(size_t)qA * S_LEN + kvr] * (-8e9f);
        sA1[r] += mask[(size_t)qA * S_LEN + kvr + 32] * (-8e9f);
        sB0[r] += mask[(size_t)qB * S_LEN + kvr] * (-8e9f);
        sB1[r] += mask[(size_t)qB * S_LEN + kvr + 32] * (-8e9f);
      }
    }

    // p = exp2(raw*K2 - C2') -- single v_exp each
#pragma unroll
    for (int r = 0; r < 16; ++r) {
      sA0[r] = ex2(fmaf(sA0[r], K2, -C2));
      sA1[r] = ex2(fmaf(sA1[r], K2, -C2));
      sB0[r] = ex2(fmaf(sB0[r], K2, -C2));
      sB1[r] = ex2(fmaf(sB1[r], K2, -C2));
    }

    U4 pfA[4], pfB[4];
    pack(sA0, sA1, pfA);
    pack(sB0, sB1, pfB);

    // PV both streams: each va read feeds 2 MFMAs; ones-MFMA denominators
    const char* vr0 = VtB + (size_t)cl * 128;
    const char* vr1 = VtB + (size_t)(32 + cl) * 128;
    __builtin_amdgcn_s_setprio(1);
#pragma unroll
    for (int c = 0; c < 4; ++c) {
      const unsigned off = ((unsigned)(hi * 16 + 32 * c)) ^ swz;
      F8 va0, va1;
      va0.s = *(const s8v*)(vr0 + off);
      va1.s = *(const s8v*)(vr1 + off);
      oA0 = __builtin_amdgcn_mfma_f32_32x32x16_bf16(va0.b, pfA[c].b, oA0, 0, 0, 0);
      oB0 = __builtin_amdgcn_mfma_f32_32x32x16_bf16(va0.b, pfB[c].b, oB0, 0, 0, 0);
      oA1 = __builtin_amdgcn_mfma_f32_32x32x16_bf16(va1.b, pfA[c].b, oA1, 0, 0, 0);
      oB1 = __builtin_amdgcn_mfma_f32_32x32x16_bf16(va1.b, pfB[c].b, oB1, 0, 0, 0);
      sA  = __builtin_amdgcn_mfma_f32_32x32x16_bf16(ones.b, pfA[c].b, sA, 0, 0, 0);
      sB  = __builtin_amdgcn_mfma_f32_32x32x16_bf16(ones.b, pfB[c].b, sB, 0, 0, 0);
    }
    __builtin_amdgcn_s_setprio(0);

    __syncthreads();
    cur ^= 1;
  }

  // ---- combine halves via LDS overlay (K/V buffers dead) ----
  float* Osh = (float*)smem;                       // [128 q][65] fp32
  float* Lsh = (float*)(smem + 33280);             // [128] l-partials
  const int qrA = wq2 * 64 + cl, qrB = qrA + 32;
  if (half) {
#pragma unroll
    for (int u = 0; u < 4; ++u) {
      const int d0 = 8 * u + 4 * hi;
#pragma unroll
      for (int r = 0; r < 4; ++r) {
        Osh[qrA * 65 + d0 + r]      = oA0[4 * u + r];
        Osh[qrA * 65 + 32 + d0 + r] = oA1[4 * u + r];
        Osh[qrB * 65 + d0 + r]      = oB0[4 * u + r];
        Osh[qrB * 65 + 32 + d0 + r] = oB1[4 * u + r];
      }
    }
    if (hi == 0) { Lsh[qrA] = sA[0]; Lsh[qrB] = sB[0]; }
  }
  __syncthreads();
  if (!half) {
    const float invA = 1.f / (sA[0] + Lsh[qrA]);
    const float invB = 1.f / (sB[0] + Lsh[qrB]);
    const int b = bh >> 3, h = bh & 7;
    ushort* opA = Obf + ((size_t)(b * S_LEN + qA)) * DM + h * DH;
    ushort* opB = Obf + ((size_t)(b * S_LEN + qB)) * DM + h * DH;
#pragma unroll
    for (int u = 0; u < 4; ++u) {
      const int d0 = 8 * u + 4 * hi;
      float a0 = (oA0[4 * u]     + Osh[qrA * 65 + d0])     * invA;
      float a1 = (oA0[4 * u + 1] + Osh[qrA * 65 + d0 + 1]) * invA;
      float a2 = (oA0[4 * u + 2] + Osh[qrA * 65 + d0 + 2]) * invA;
      float a3 = (oA0[4 * u + 3] + Osh[qrA * 65 + d0 + 3]) * invA;
      *(uint2*)(opA + d0) = make_uint2(pk2(a0, a1), pk2(a2, a3));
      a0 = (oA1[4 * u]     + Osh[qrA * 65 + 32 + d0])     * invA;
      a1 = (oA1[4 * u + 1] + Osh[qrA * 65 + 32 + d0 + 1]) * invA;
      a2 = (oA1[4 * u + 2] + Osh[qrA * 65 + 32 + d0 + 2]) * invA;
      a3 = (oA1[4 * u + 3] + Osh[qrA * 65 + 32 + d0 + 3]) * invA;
      *(uint2*)(opA + 32 + d0) = make_uint2(pk2(a0, a1), pk2(a2, a3));
      a0 = (oB0[4 * u]     + Osh[qrB * 65 + d0])     * invB;
      a1 = (oB0[4 * u + 1] + Osh[qrB * 65 + d0 + 1]) * invB;
      a2 = (oB0[4 * u + 2] + Osh[qrB * 65 + d0 + 2]) * invB;
      a3 = (oB0[4 * u + 3] + Osh[qrB * 65 + d0 + 3]) * invB;
      *(uint2*)(opB + d0) = make_uint2(pk2(a0, a1), pk2(a2, a3));
      a0 = (oB1[4 * u]     + Osh[qrB * 65 + 32 + d0])     * invB;
      a1 = (oB1[4 * u + 1] + Osh[qrB * 65 + 32 + d0 + 1]) * invB;
      a2 = (oB1[4 * u + 2] + Osh[qrB * 65 + 32 + d0 + 2]) * invB;
      a3 = (oB1[4 * u + 3] + Osh[qrB * 65 + 32 + d0 + 3]) * invB;
      *(uint2*)(opB + 32 + d0) = make_uint2(pk2(a0, a1), pk2(a2, a3));
    }
  }
}

// ---------------- launch ----------------
extern "C" void kernel_launch(void* const* d_in, const int* in_sizes, int n_in,
                              void* d_out, int out_size, void* d_ws, size_t ws_size,
                              hipStream_t stream) {
  (void)in_sizes; (void)n_in; (void)out_size; (void)ws_size;
  const float* q    = (const float*)d_in[0];
  const float* k    = (const float*)d_in[1];
  const float* v    = (const float*)d_in[2];
  const float* mask = (const float*)d_in[3];
  const float* wq   = (const float*)d_in[4];
  const float* bq   = (const float*)d_in[5];
  const float* wk   = (const float*)d_in[6];
  const float* bk   = (const float*)d_in[7];
  const float* wv   = (const float*)d_in[8];
  const float* bv   = (const float*)d_in[9];
  const float* wo   = (const float*)d_in[10];
  const float* bo   = (const float*)d_in[11];

  char* ws = (char*)d_ws;
  const size_t SZX = (size_t)8192 * 512 * 2;
  ushort* Obf = (ushort*)(ws + 0 * SZX);
  ushort* Qh  = (ushort*)(ws + 3 * SZX);
  ushort* Kh  = (ushort*)(ws + 4 * SZX);
  ushort* Vt  = (ushort*)(ws + 5 * SZX);
  const size_t SZW = (size_t)512 * 512 * 2;
  ushort* Wtq = (ushort*)(ws + 6 * SZX + 0 * SZW);
  ushort* Wtk = (ushort*)(ws + 6 * SZX + 1 * SZW);
  ushort* Wtv = (ushort*)(ws + 6 * SZX + 2 * SZW);
  ushort* Wto = (ushort*)(ws + 6 * SZX + 3 * SZW);
  int* flag   = (int*)(ws + 6 * SZX + 4 * SZW);

  hipMemsetAsync(flag, 0, 4, stream);
  prep<<<dim3(2048, 3), 256, 0, stream>>>(mask, wq, wk, wv, wo,
                                          Wtq, Wtk, Wtv, Wto, flag);
  gemm_qkv<<<768, 256, 0, stream>>>(q, k, v, Wtq, Wtk, Wtv,
                                    bq, bk, bv, Qh, Kh, Vt);
  attn<<<512, 256, 0, stream>>>(Qh, Kh, Vt, mask, flag, Obf);
  gemm_o2<<<512, 256, 0, stream>>>(Obf, Wto, bo, (float*)d_out);
}

// Round 16
// 108.809 us; speedup vs baseline: 1.1325x; 1.1325x over previous
//
#include <hip/hip_runtime.h>
#include <hip/hip_bf16.h>

#define S_LEN 2048
#define DM    512
#define NH    8
#define DH    64

typedef float  f4   __attribute__((ext_vector_type(4)));
typedef float  f16v __attribute__((ext_vector_type(16)));
typedef short  s8v  __attribute__((ext_vector_type(8)));
typedef __bf16 b8v  __attribute__((ext_vector_type(8)));
union F8 { s8v s; b8v b; };
union U4 { unsigned u[4]; s8v s; b8v b; };

typedef __attribute__((address_space(1))) const void gas_t;
typedef __attribute__((address_space(3))) void       las_t;

__device__ __forceinline__ void gl16(const void* g, void* l) {
  __builtin_amdgcn_global_load_lds((gas_t*)g, (las_t*)l, 16, 0, 0);
}

__device__ __forceinline__ ushort f2bf(float x) {
  unsigned u = __float_as_uint(x);
  u += 0x7FFFu + ((u >> 16) & 1u);   // round-to-nearest-even
  return (ushort)(u >> 16);
}
// packed f32x2 -> bf16x2, RNE (compiler path per m240)
__device__ __forceinline__ unsigned pk2(float a, float b) {
  union { __hip_bfloat162 h; unsigned u; } cv;
  cv.h = __float22bfloat162_rn(make_float2(a, b));
  return cv.u;
}
// packed f32x2 -> bf16x2 by TRUNCATION: single v_perm_b32.
// (round-bias is pre-compensated in the exp2 constant C2')
__device__ __forceinline__ unsigned pkt(float a, float b) {
  return __builtin_amdgcn_perm(__float_as_uint(b), __float_as_uint(a),
                               0x07060302u);
}
// 1-instr exp2
__device__ __forceinline__ float ex2(float x) {
#if __has_builtin(__builtin_amdgcn_exp2f)
  return __builtin_amdgcn_exp2f(x);
#else
  return exp2f(x);
#endif
}

// (r_lo, r_hi) = permlane32_swap(a, b)
__device__ __forceinline__ void plswap(unsigned a, unsigned b,
                                       unsigned& lo, unsigned& hi2) {
#if __has_builtin(__builtin_amdgcn_permlane32_swap)
  auto r = __builtin_amdgcn_permlane32_swap((int)a, (int)b, false, false);
  lo  = (unsigned)r[0];
  hi2 = (unsigned)r[1];
#else
  const bool ish = (threadIdx.x & 32) != 0;
  const unsigned sa = (unsigned)__shfl_xor((int)a, 32);
  const unsigned sb = (unsigned)__shfl_xor((int)b, 32);
  lo  = ish ? sb : a;
  hi2 = ish ? b  : sa;
#endif
}

// --- slim prep: mask nonzero scan + weight transpose ---
__global__ void prep(const float* __restrict__ mask,
                     const float* __restrict__ w0, const float* __restrict__ w1,
                     const float* __restrict__ w2, const float* __restrict__ w3,
                     ushort* __restrict__ o0, ushort* __restrict__ o1,
                     ushort* __restrict__ o2, ushort* __restrict__ o3,
                     int* __restrict__ flag) {
  const int z = blockIdx.y;
  if (z == 2) {
    const int bx = blockIdx.x;
    if (bx >= 1024) return;
    const int w = bx >> 8;
    const float* src = (w == 0) ? w0 : (w == 1) ? w1 : (w == 2) ? w2 : w3;
    ushort* dst = (w == 0) ? o0 : (w == 1) ? o1 : (w == 2) ? o2 : o3;
    __shared__ float tile[32][33];
    const int tx = threadIdx.x & 31, ty = threadIdx.x >> 5;   // 32 x 8
    const int k0 = (bx & 15) * 32, n0 = ((bx >> 4) & 15) * 32;
#pragma unroll
    for (int i = 0; i < 4; ++i)
      tile[ty + i * 8][tx] = src[(size_t)(k0 + ty + i * 8) * DM + n0 + tx];
    __syncthreads();
#pragma unroll
    for (int i = 0; i < 4; ++i)
      dst[(size_t)(n0 + ty + i * 8) * DM + k0 + tx] = f2bf(tile[tx][ty + i * 8]);
    return;
  }
  const size_t i = (((size_t)z * 2048 + blockIdx.x) * 256 + threadIdx.x) * 4;
  const float4 m4 = *(const float4*)(mask + i);
  const bool nz = (m4.x != 0.f) | (m4.y != 0.f) | (m4.z != 0.f) | (m4.w != 0.f);
  if (nz) atomicOr(flag, 1);
}

// ------- QKV GEMM: fp32 A read + in-staging bf16 convert (reg-staged, T14),
// bf16 B via global_load_lds; 2-buf LDS; tn-siblings of a tm share an XCD -------
__global__ __launch_bounds__(256) void gemm_qkv(
    const float* __restrict__ Qf, const float* __restrict__ Kf,
    const float* __restrict__ Vf, const ushort* __restrict__ Wtq,
    const ushort* __restrict__ Wtk, const ushort* __restrict__ Wtv,
    const float* __restrict__ bq, const float* __restrict__ bk,
    const float* __restrict__ bv, ushort* __restrict__ Qh,
    ushort* __restrict__ Kh, ushort* __restrict__ Vt) {
  __shared__ ushort As[2 * 128 * 32], Bs[2 * 128 * 32];   // 2-buf, 32KB

  const int b = blockIdx.x;
  const int xcd = b & 7, i = b >> 3;               // i in [0,96)
  const int z = i >> 5, j = i & 31;
  const int tm = xcd * 8 + (j >> 2), tn = j & 3;
  const float* A = (z == 0) ? Qf : (z == 1) ? Kf : Vf;
  const ushort* Bt = (z == 0) ? Wtq : (z == 1) ? Wtk : Wtv;
  const float* bias = (z == 0) ? bq : (z == 1) ? bk : bv;
  ushort* out = (z == 0) ? Qh : (z == 1) ? Kh : Vt;
  const int mode = (z == 2) ? 1 : 0;

  const int tid  = threadIdx.x;
  const int lane = tid & 63, wave = tid >> 6;
  const int ql = lane & 15, lg = lane >> 4;
  const int wr = wave >> 1, wc = wave & 1;

  const int srow = wave * 32 + (lane >> 2);        // local staging row
  const float* gA0 = A + (size_t)(tm * 128 + srow) * 512 + (lane & 3) * 8;
  const float* gA1 = gA0 + 16 * 512;
  const char*  gB  = (const char*)(Bt + (size_t)(tn * 128 + srow) * 512) +
                     (lane & 3) * 16;

  float4 ar[4];
  auto loadA = [&](int kt) {                       // issue early: hides HBM lat
    const float* p0 = gA0 + kt * 32;
    const float* p1 = gA1 + kt * 32;
    ar[0] = *(const float4*)p0; ar[1] = *(const float4*)(p0 + 4);
    ar[2] = *(const float4*)p1; ar[3] = *(const float4*)(p1 + 4);
  };
  auto writeA = [&](int buf) {                     // cvt + ds_write (late)
    char* d = (char*)As + buf * 8192 + srow * 64 + (lane & 3) * 16;
    *(uint4*)d = make_uint4(pk2(ar[0].x, ar[0].y), pk2(ar[0].z, ar[0].w),
                            pk2(ar[1].x, ar[1].y), pk2(ar[1].z, ar[1].w));
    *(uint4*)(d + 16 * 64) =
        make_uint4(pk2(ar[2].x, ar[2].y), pk2(ar[2].z, ar[2].w),
                   pk2(ar[3].x, ar[3].y), pk2(ar[3].z, ar[3].w));
  };
  auto stageB = [&](int kt, int buf) {
    char* lB = (char*)Bs + buf * 8192 + wave * 2048;
    const size_t gofs = (size_t)kt * 64;
    gl16(gB + gofs, lB);
    gl16(gB + gofs + 16 * 512 * 2, lB + 1024);
  };

  f4 acc[4][4] = {};

  loadA(0);
  stageB(0, 0);
  writeA(0);
  __syncthreads();

  int cur = 0;
  for (int kt = 0; kt < 16; ++kt) {
    if (kt + 1 < 16) { loadA(kt + 1); stageB(kt + 1, cur ^ 1); }
    const ushort* Ab = As + cur * 4096;
    const ushort* Bb = Bs + cur * 4096;
    F8 af[4], bf[4];
#pragma unroll
    for (int ii = 0; ii < 4; ++ii) {
      af[ii].s = *(const s8v*)(Ab + (wr * 64 + ii * 16 + ql) * 32 + lg * 8);
      bf[ii].s = *(const s8v*)(Bb + (wc * 64 + ii * 16 + ql) * 32 + lg * 8);
    }
#pragma unroll
    for (int ii = 0; ii < 4; ++ii)
#pragma unroll
      for (int jj = 0; jj < 4; ++jj)
        acc[ii][jj] = __builtin_amdgcn_mfma_f32_16x16x32_bf16(
            af[ii].b, bf[jj].b, acc[ii][jj], 0, 0, 0);
    if (kt + 1 < 16) writeA(cur ^ 1);              // lands before next barrier
    __syncthreads();
    cur ^= 1;
  }

#pragma unroll
  for (int ii = 0; ii < 4; ++ii) {
#pragma unroll
    for (int jj = 0; jj < 4; ++jj) {
      const int n = tn * 128 + wc * 64 + jj * 16 + ql;
      const float bz = bias[n];
#pragma unroll
      for (int r = 0; r < 4; ++r) {
        const int m = tm * 128 + wr * 64 + ii * 16 + lg * 4 + r;
        const float val = acc[ii][jj][r] + bz;
        const int bb = m >> 11, s = m & 2047, h = n >> 6, d = n & 63;
        if (mode == 0)
          out[((size_t)(bb * NH + h) * S_LEN + s) * DH + d] = f2bf(val);
        else
          out[((size_t)(bb * NH + h) * DH + d) * S_LEN + s] = f2bf(val);
      }
    }
  }
}

// ------- output projection: 128x64 tiles, 2-phase staging -------
__global__ __launch_bounds__(256) void gemm_o2(
    const ushort* __restrict__ Obf, const ushort* __restrict__ Wto,
    const float* __restrict__ bo, float* __restrict__ out) {
  __shared__ ushort As[2 * 128 * 32];              // 2 x 8KB
  __shared__ ushort Bs[2 * 64 * 32];               // 2 x 4KB
  const int bidx = blockIdx.x;
  const int xcd = bidx & 7, ii = bidx >> 3;        // ii in [0,64)
  const int tm = xcd * 8 + (ii >> 3), tn = ii & 7;
  const int tid  = threadIdx.x;
  const int lane = tid & 63, wave = tid >> 6;
  const int ql = lane & 15, lg = lane >> 4;
  const int wr = wave >> 1, wc = wave & 1;

  const int rowA0 = tid >> 2,         offA0 = (tid & 3) * 16;
  const int rowA1 = (256 + tid) >> 2, offA1 = ((256 + tid) & 3) * 16;
  const int rowB  = tid >> 2,         offB  = (tid & 3) * 16;
  const char* gA0 = (const char*)(Obf + (size_t)(tm * 128 + rowA0) * 512) + offA0;
  const char* gA1 = (const char*)(Obf + (size_t)(tm * 128 + rowA1) * 512) + offA1;
  const char* gB  = (const char*)(Wto + (size_t)(tn * 64 + rowB) * 512) + offB;

  auto stage = [&](int kt, int buf) {
    const size_t gofs = (size_t)kt * 64;
    char* lA0 = (char*)As + buf * 8192 + wave * 1024;
    char* lA1 = (char*)As + buf * 8192 + 4096 + wave * 1024;
    char* lB  = (char*)Bs + buf * 4096 + wave * 1024;
    gl16(gA0 + gofs, lA0);
    gl16(gA1 + gofs, lA1);
    gl16(gB + gofs, lB);
  };

  f4 acc[4][2] = {};

  stage(0, 0);
  __syncthreads();

  int cur = 0;
  for (int kt = 0; kt < 16; ++kt) {
    if (kt + 1 < 16) stage(kt + 1, cur ^ 1);
    const ushort* Ab = As + cur * 4096;
    const ushort* Bb = Bs + cur * 2048;
    F8 af[4], bf[2];
#pragma unroll
    for (int i = 0; i < 4; ++i)
      af[i].s = *(const s8v*)(Ab + (wr * 64 + i * 16 + ql) * 32 + lg * 8);
#pragma unroll
    for (int j = 0; j < 2; ++j)
      bf[j].s = *(const s8v*)(Bb + (wc * 32 + j * 16 + ql) * 32 + lg * 8);
#pragma unroll
    for (int i = 0; i < 4; ++i)
#pragma unroll
      for (int j = 0; j < 2; ++j)
        acc[i][j] = __builtin_amdgcn_mfma_f32_16x16x32_bf16(af[i].b, bf[j].b,
                                                            acc[i][j], 0, 0, 0);
    __syncthreads();
    cur ^= 1;
  }

#pragma unroll
  for (int i = 0; i < 4; ++i)
#pragma unroll
    for (int j = 0; j < 2; ++j) {
      const int n = tn * 64 + wc * 32 + j * 16 + ql;
      const float bz = bo[n];
#pragma unroll
      for (int r = 0; r < 4; ++r) {
        const int m = tm * 128 + wr * 64 + i * 16 + lg * 4 + r;
        out[(size_t)m * DM + n] = acc[i][j][r] + bz;
      }
    }
}

// ------- flash attention: 2 KV-tiles per barrier (intra-wave ILP) -------
// grid = 512 (XCD-remapped, 32 bh * 16 qblocks); 4 waves; wave = 32 q rows.
// 4-buffer K/V LDS (64KB -> 2 blocks/CU); each iteration stages the next
// tile-PAIR and computes two INDEPENDENT per-tile chains (QK/exp/pack/PV x2)
// that the scheduler interleaves -> 2x chain ILP, half the barriers.
__global__ __launch_bounds__(256, 2) void attn(
    const ushort* __restrict__ Qh, const ushort* __restrict__ Kh,
    const ushort* __restrict__ Vt, const float* __restrict__ mask,
    const int* __restrict__ flagp, ushort* __restrict__ Obf) {
  __shared__ ushort Ks[4][4096];                   // 4 x 8KB  [64 kv][64 d]
  __shared__ ushort Vs[4][4096];                   // 4 x 8KB  [64 d][64 kv]

  const float K2 = 0.18033688011f;                 // 0.125 * log2(e)
  const float C2 = 17.3095245361f;                 // 12*log2(e) - log2(1+2^-9)

  const int bid = (blockIdx.x & 7) * 64 + (blockIdx.x >> 3);
  const int bh = bid >> 4, qb = bid & 15;
  const int tid = threadIdx.x, lane = tid & 63, wave = tid >> 6;
  const int cl = lane & 31, hi = lane >> 5;
  const int q = qb * 128 + wave * 32 + cl;         // this lane's q row
  const bool um = (*flagp) != 0;
  const char* KbC = (const char*)(Kh + (size_t)bh * S_LEN * DH);
  const char* VbC = (const char*)(Vt + (size_t)bh * DH * S_LEN);
  const unsigned swz = (unsigned)((cl & 7) << 4);

  int kofs[2], vofs[2];
#pragma unroll
  for (int c = 0; c < 2; ++c) {
    const int ui  = wave * 128 + c * 64 + lane;    // 16B-unit index in 8KB tile
    const int row = ui >> 3, u = ui & 7;
    const int xu  = u ^ (row & 7);
    kofs[c] = row * 128  + (xu << 4);              // K rows are 128B
    vofs[c] = row * 4096 + (xu << 4);              // V^T rows are S*2 = 4096B
  }

  // Q B-frags: lane holds Q[q][d = hi*8 + 16c .. +8]
  F8 qf[4];
#pragma unroll
  for (int c = 0; c < 4; ++c)
    qf[c].s = *(const s8v*)(Qh + ((size_t)bh * S_LEN + q) * DH + hi * 8 + 16 * c);

  F8 ones;
#pragma unroll
  for (int i = 0; i < 8; ++i) ones.s[i] = (short)0x3F80;  // bf16 1.0

  f16v oacc0 = {}, oacc1 = {}, sacc = {};

  auto stage = [&](int kt, int buf) {
    const char* kg = KbC + (size_t)kt * 8192;      // 64 rows * 128B
    const char* vg = VbC + (size_t)kt * 128;       // 64 cols * 2B
    char* kl = (char*)&Ks[buf][0] + wave * 2048;
    char* vl = (char*)&Vs[buf][0] + wave * 2048;
    gl16(kg + kofs[0], kl);
    gl16(kg + kofs[1], kl + 1024);
    gl16(vg + vofs[0], vl);
    gl16(vg + vofs[1], vl + 1024);
  };

  // computes one tile's QK^T scores into s0/s1 (raw logits)
  auto qk = [&](const char* KtB, f16v& s0, f16v& s1) {
    const char* kr0 = KtB + (size_t)cl * 128;
    const char* kr1 = KtB + (size_t)(32 + cl) * 128;
#pragma unroll
    for (int c = 0; c < 4; ++c) {
      const unsigned off = ((unsigned)(hi * 16 + 32 * c)) ^ swz;
      F8 ka0, ka1;
      ka0.s = *(const s8v*)(kr0 + off);
      ka1.s = *(const s8v*)(kr1 + off);
      s0 = __builtin_amdgcn_mfma_f32_32x32x16_bf16(ka0.b, qf[c].b, s0, 0, 0, 0);
      s1 = __builtin_amdgcn_mfma_f32_32x32x16_bf16(ka1.b, qf[c].b, s1, 0, 0, 0);
    }
  };
  auto softmax_pack = [&](f16v& s0, f16v& s1, int kv0, U4* pf) {
    if (um) {
#pragma unroll
      for (int r = 0; r < 16; ++r) {
        const int kvr = kv0 + (r & 3) + 8 * (r >> 2) + 4 * hi;
        s0[r] += mask[(size_t)q * S_LEN + kvr] * (-8e9f);
        s1[r] += mask[(size_t)q * S_LEN + kvr + 32] * (-8e9f);
      }
    }
#pragma unroll
    for (int r = 0; r < 16; ++r) {
      s0[r] = ex2(fmaf(s0[r], K2, -C2));
      s1[r] = ex2(fmaf(s1[r], K2, -C2));
    }
    unsigned P0[4][2], P1[4][2];
#pragma unroll
    for (int u = 0; u < 4; ++u)
#pragma unroll
      for (int e = 0; e < 2; ++e) {
        P0[u][e] = pkt(s0[4 * u + 2 * e], s0[4 * u + 2 * e + 1]);
        P1[u][e] = pkt(s1[4 * u + 2 * e], s1[4 * u + 2 * e + 1]);
      }
#pragma unroll
    for (int half = 0; half < 2; ++half)
#pragma unroll
      for (int e = 0; e < 2; ++e) {
        unsigned lo, h2;
        plswap(P0[2 * half][e], P0[2 * half + 1][e], lo, h2);
        pf[half].u[e] = lo; pf[half].u[2 + e] = h2;
        plswap(P1[2 * half][e], P1[2 * half + 1][e], lo, h2);
        pf[2 + half].u[e] = lo; pf[2 + half].u[2 + e] = h2;
      }
  };
  auto pv = [&](const char* VtB, U4* pf) {
    const char* vr0 = VtB + (size_t)cl * 128;
    const char* vr1 = VtB + (size_t)(32 + cl) * 128;
#pragma unroll
    for (int c = 0; c < 4; ++c) {
      const unsigned off = ((unsigned)(hi * 16 + 32 * c)) ^ swz;
      F8 va0, va1;
      va0.s = *(const s8v*)(vr0 + off);
      va1.s = *(const s8v*)(vr1 + off);
      oacc0 = __builtin_amdgcn_mfma_f32_32x32x16_bf16(va0.b, pf[c].b, oacc0, 0, 0, 0);
      oacc1 = __builtin_amdgcn_mfma_f32_32x32x16_bf16(va1.b, pf[c].b, oacc1, 0, 0, 0);
      sacc  = __builtin_amdgcn_mfma_f32_32x32x16_bf16(ones.b, pf[c].b, sacc, 0, 0, 0);
    }
  };

  // prologue: stage tile pair 0 (tiles 0,1 -> buffers 0,1)
  stage(0, 0);
  stage(1, 1);
  __syncthreads();

  int pair = 0;
  for (int it = 0; it < 16; ++it) {
    if (it + 1 < 16) {                             // stage next pair
      stage(2 * it + 2, (pair ^ 1) * 2);
      stage(2 * it + 3, (pair ^ 1) * 2 + 1);
    }
    const char* KtA = (const char*)&Ks[pair * 2][0];
    const char* KtB2 = (const char*)&Ks[pair * 2 + 1][0];
    const char* VtA = (const char*)&Vs[pair * 2][0];
    const char* VtB2 = (const char*)&Vs[pair * 2 + 1][0];

    // two independent chains; scheduler interleaves them
    f16v sA0 = {}, sA1 = {}, sB0 = {}, sB1 = {};
    __builtin_amdgcn_s_setprio(1);
    qk(KtA, sA0, sA1);
    qk(KtB2, sB0, sB1);
    __builtin_amdgcn_s_setprio(0);
    U4 pfA[4], pfB[4];
    softmax_pack(sA0, sA1, (2 * it) * 64, pfA);
    softmax_pack(sB0, sB1, (2 * it + 1) * 64, pfB);
    __builtin_amdgcn_s_setprio(1);
    pv(VtA, pfA);
    pv(VtB2, pfB);
    __builtin_amdgcn_s_setprio(0);

    __syncthreads();
    pair ^= 1;
  }

  // sacc rows identical = column sums of P over all kv
  const float inv = 1.f / sacc[0];
  const int b = bh >> 3, h = bh & 7;
  ushort* op = Obf + ((size_t)(b * S_LEN + q)) * DM + h * DH;
#pragma unroll
  for (int u = 0; u < 4; ++u) {
    const int d0 = 8 * u + 4 * hi;
    *(uint2*)(op + d0) =
        make_uint2(pk2(oacc0[4 * u] * inv, oacc0[4 * u + 1] * inv),
                   pk2(oacc0[4 * u + 2] * inv, oacc0[4 * u + 3] * inv));
    *(uint2*)(op + 32 + d0) =
        make_uint2(pk2(oacc1[4 * u] * inv, oacc1[4 * u + 1] * inv),
                   pk2(oacc1[4 * u + 2] * inv, oacc1[4 * u + 3] * inv));
  }
}

// ---------------- launch ----------------
extern "C" void kernel_launch(void* const* d_in, const int* in_sizes, int n_in,
                              void* d_out, int out_size, void* d_ws, size_t ws_size,
                              hipStream_t stream) {
  (void)in_sizes; (void)n_in; (void)out_size; (void)ws_size;
  const float* q    = (const float*)d_in[0];
  const float* k    = (const float*)d_in[1];
  const float* v    = (const float*)d_in[2];
  const float* mask = (const float*)d_in[3];
  const float* wq   = (const float*)d_in[4];
  const float* bq   = (const float*)d_in[5];
  const float* wk   = (const float*)d_in[6];
  const float* bk   = (const float*)d_in[7];
  const float* wv   = (const float*)d_in[8];
  const float* bv   = (const float*)d_in[9];
  const float* wo   = (const float*)d_in[10];
  const float* bo   = (const float*)d_in[11];

  char* ws = (char*)d_ws;
  const size_t SZX = (size_t)8192 * 512 * 2;
  ushort* Obf = (ushort*)(ws + 0 * SZX);
  ushort* Qh  = (ushort*)(ws + 3 * SZX);
  ushort* Kh  = (ushort*)(ws + 4 * SZX);
  ushort* Vt  = (ushort*)(ws + 5 * SZX);
  const size_t SZW = (size_t)512 * 512 * 2;
  ushort* Wtq = (ushort*)(ws + 6 * SZX + 0 * SZW);
  ushort* Wtk = (ushort*)(ws + 6 * SZX + 1 * SZW);
  ushort* Wtv = (ushort*)(ws + 6 * SZX + 2 * SZW);
  ushort* Wto = (ushort*)(ws + 6 * SZX + 3 * SZW);
  int* flag   = (int*)(ws + 6 * SZX + 4 * SZW);

  hipMemsetAsync(flag, 0, 4, stream);
  prep<<<dim3(2048, 3), 256, 0, stream>>>(mask, wq, wk, wv, wo,
                                          Wtq, Wtk, Wtv, Wto, flag);
  gemm_qkv<<<768, 256, 0, stream>>>(q, k, v, Wtq, Wtk, Wtv,
                                    bq, bk, bv, Qh, Kh, Vt);
  attn<<<512, 256, 0, stream>>>(Qh, Kh, Vt, mask, flag, Obf);
  gemm_o2<<<512, 256, 0, stream>>>(Obf, Wto, bo, (float*)d_out);
}